// Round 4
// baseline (38.741 us; speedup 1.0000x reference)
//
#include <hip/hip_runtime.h>

#define NB 2048
#define NC 512
#define ND 256
#define VIG 0.75f

// ---------------- kernel 1: cat[512][256] -> catT[256][512] in d_ws ----------
__global__ __launch_bounds__(256) void transpose_cat(const float* __restrict__ cat,
                                                     float* __restrict__ catT) {
  __shared__ float tile[64][65];
  const int t = threadIdx.x;
  const int c0 = blockIdx.x * 64;
  const int d0 = blockIdx.y * 64;
  const int tr = t >> 4;        // 0..15
  const int tc = (t & 15) * 4;  // 0,4,...,60
#pragma unroll
  for (int ii = 0; ii < 4; ++ii) {
    const int ci = ii * 16 + tr;
    const float4 v =
        *reinterpret_cast<const float4*>(cat + (size_t)(c0 + ci) * ND + d0 + tc);
    tile[ci][tc + 0] = v.x;
    tile[ci][tc + 1] = v.y;
    tile[ci][tc + 2] = v.z;
    tile[ci][tc + 3] = v.w;
  }
  __syncthreads();
#pragma unroll
  for (int ii = 0; ii < 4; ++ii) {
    const int di = ii * 16 + tr;
    float4 v;
    v.x = tile[tc + 0][di];
    v.y = tile[tc + 1][di];
    v.z = tile[tc + 2][di];
    v.w = tile[tc + 3][di];
    *reinterpret_cast<float4*>(catT + (size_t)(d0 + di) * NC + c0 + tc) = v;
  }
}

// ---------------- kernel 2: main, no LDS staging, no main-loop barriers ------
// Block = 4 rows x 512 cats. 256 threads: half = t>>7 owns rows {2h, 2h+1},
// lane group g = t&127 owns cats [4g, 4g+4). catT reads: 1KB coalesced per
// wave-instr, L2-resident. x reads wave-uniform -> scalar path.
__global__ __launch_bounds__(256) void fuzzy_catT(const float* __restrict__ x,
                                                  const float* __restrict__ catT,
                                                  float* __restrict__ out) {
  __shared__ float part[4][4];
  __shared__ float rs[4];
  __shared__ float red[4][2][2];  // [row][cat-half][val, idx]

  const int t = threadIdx.x;
  const int lane = t & 63;
  const int w = t >> 6;
  const int half = t >> 7;  // wave-uniform
  const int g = t & 127;
  const int c4 = g * 4;
  const int bm0 = blockIdx.x * 4;

  // row sums — summation order identical to rounds 1-3 (bit-exact)
  if (t < 16) {
    const int r = t >> 2, seg = t & 3;
    const float4* xr =
        reinterpret_cast<const float4*>(x + (size_t)(bm0 + r) * ND + seg * 64);
    float s = 0.f;
#pragma unroll
    for (int i = 0; i < 16; ++i) {
      float4 v = xr[i];
      s += v.x + v.y + v.z + v.w;
    }
    part[r][seg] = s;
  }
  __syncthreads();
  if (t < 4) rs[t] = part[t][0] + part[t][1] + part[t][2] + part[t][3];
  __syncthreads();

  const int row0 = __builtin_amdgcn_readfirstlane(bm0 + half * 2);
  const float* xr = x + (size_t)row0 * ND;  // rows row0, row0+1 (uniform)
  const float* cp0 = catT + c4;             // serves k, k+1
  const float* cp1 = catT + 2 * NC + c4;    // serves k+2, k+3

  float a00 = 0.f, a01 = 0.f, a02 = 0.f, a03 = 0.f;
  float a10 = 0.f, a11 = 0.f, a12 = 0.f, a13 = 0.f;

#pragma unroll 4
  for (int k = 0; k < ND; k += 4) {
    const float4 cv0 = *reinterpret_cast<const float4*>(cp0);
    const float4 cv1 = *reinterpret_cast<const float4*>(cp0 + NC);
    const float4 cv2 = *reinterpret_cast<const float4*>(cp1);
    const float4 cv3 = *reinterpret_cast<const float4*>(cp1 + NC);
    cp0 += 4 * NC;
    cp1 += 4 * NC;
    const float4 x0 = *reinterpret_cast<const float4*>(xr + k);       // row0
    const float4 x1 = *reinterpret_cast<const float4*>(xr + ND + k);  // row0+1
    a00 += fminf(x0.x, cv0.x); a00 += fminf(x0.y, cv1.x);
    a00 += fminf(x0.z, cv2.x); a00 += fminf(x0.w, cv3.x);
    a01 += fminf(x0.x, cv0.y); a01 += fminf(x0.y, cv1.y);
    a01 += fminf(x0.z, cv2.y); a01 += fminf(x0.w, cv3.y);
    a02 += fminf(x0.x, cv0.z); a02 += fminf(x0.y, cv1.z);
    a02 += fminf(x0.z, cv2.z); a02 += fminf(x0.w, cv3.z);
    a03 += fminf(x0.x, cv0.w); a03 += fminf(x0.y, cv1.w);
    a03 += fminf(x0.z, cv2.w); a03 += fminf(x0.w, cv3.w);
    a10 += fminf(x1.x, cv0.x); a10 += fminf(x1.y, cv1.x);
    a10 += fminf(x1.z, cv2.x); a10 += fminf(x1.w, cv3.x);
    a11 += fminf(x1.x, cv0.y); a11 += fminf(x1.y, cv1.y);
    a11 += fminf(x1.z, cv2.y); a11 += fminf(x1.w, cv3.y);
    a12 += fminf(x1.x, cv0.z); a12 += fminf(x1.y, cv1.z);
    a12 += fminf(x1.z, cv2.z); a12 += fminf(x1.w, cv3.z);
    a13 += fminf(x1.x, cv0.w); a13 += fminf(x1.y, cv1.w);
    a13 += fminf(x1.z, cv2.w); a13 += fminf(x1.w, cv3.w);
  }

  // epilogue: divide, threshold, store, fused argmax
  const float r0 = rs[half * 2], r1 = rs[half * 2 + 1];
  float v00 = a00 / r0, v01 = a01 / r0, v02 = a02 / r0, v03 = a03 / r0;
  float v10 = a10 / r1, v11 = a11 / r1, v12 = a12 / r1, v13 = a13 / r1;
  v00 = (v00 >= VIG) ? v00 : 0.f;  v01 = (v01 >= VIG) ? v01 : 0.f;
  v02 = (v02 >= VIG) ? v02 : 0.f;  v03 = (v03 >= VIG) ? v03 : 0.f;
  v10 = (v10 >= VIG) ? v10 : 0.f;  v11 = (v11 >= VIG) ? v11 : 0.f;
  v12 = (v12 >= VIG) ? v12 : 0.f;  v13 = (v13 >= VIG) ? v13 : 0.f;

  float4 s0 = {v00, v01, v02, v03};
  float4 s1 = {v10, v11, v12, v13};
  *reinterpret_cast<float4*>(out + (size_t)row0 * NC + c4) = s0;
  *reinterpret_cast<float4*>(out + (size_t)(row0 + 1) * NC + c4) = s1;

  // argmax: in-thread (4 ascending cats, strict >), then wave shuffle
  // (lanes ascending cats within wave), then 2 cat-halves via LDS.
#pragma unroll
  for (int r = 0; r < 2; ++r) {
    float q0, q1, q2, q3;
    if (r == 0) { q0 = v00; q1 = v01; q2 = v02; q3 = v03; }
    else { q0 = v10; q1 = v11; q2 = v12; q3 = v13; }
    float bv = q0; int bi = c4;
    if (q1 > bv) { bv = q1; bi = c4 + 1; }
    if (q2 > bv) { bv = q2; bi = c4 + 2; }
    if (q3 > bv) { bv = q3; bi = c4 + 3; }
#pragma unroll
    for (int off = 32; off > 0; off >>= 1) {
      float ob = __shfl_xor(bv, off, 64);
      int oi = __shfl_xor(bi, off, 64);
      if (ob > bv || (ob == bv && oi < bi)) { bv = ob; bi = oi; }
    }
    if (lane == 0) {
      red[half * 2 + r][w & 1][0] = bv;
      red[half * 2 + r][w & 1][1] = (float)bi;
    }
  }
  __syncthreads();
  if (t < 4) {
    float bv = red[t][0][0];
    float bi = red[t][0][1];
    if (red[t][1][0] > bv) { bv = red[t][1][0]; bi = red[t][1][1]; }
    out[(size_t)NB * NC + bm0 + t] = bi;
  }
}

extern "C" void kernel_launch(void* const* d_in, const int* in_sizes, int n_in,
                              void* d_out, int out_size, void* d_ws, size_t ws_size,
                              hipStream_t stream) {
  const float* x = (const float*)d_in[0];
  const float* cat = (const float*)d_in[1];
  float* out = (float*)d_out;
  float* catT = (float*)d_ws;

  transpose_cat<<<dim3(NC / 64, ND / 64), 256, 0, stream>>>(cat, catT);
  fuzzy_catT<<<NB / 4, 256, 0, stream>>>(x, catT, out);
}

// Round 5
// 34.585 us; speedup vs baseline: 1.1202x; 1.1202x over previous
//
#include <hip/hip_runtime.h>

#define NB 2048
#define NC 512
#define ND 256
#define VIG 0.75f
#define CK 16
#define NCHK (ND / CK)  // 16 chunks

typedef __attribute__((ext_vector_type(2))) float f2;  // -> v_pk_add_f32

__device__ __forceinline__ void load_lds16(const float* g, float* l) {
  __builtin_amdgcn_global_load_lds((const __attribute__((address_space(1))) void*)g,
                                   (__attribute__((address_space(3))) void*)l,
                                   16, 0, 0);
}

// One block = 4 rows x 512 cols (R3 structure). 4 waves; wave w owns cols
// [w*128, +128); lane owns cols c0 = w*128+lane and c0+64 — packed into one
// float2 accumulator per row (scalar v_min_f32 x2 + one v_pk_add_f32).
// cat chunk staged to LDS double-buffered via global_load_lds, granule-
// swizzled. x reads are block-uniform -> scalar path. Fused argmax.
__global__ __launch_bounds__(256, 2) void fuzzy_fused(const float* __restrict__ x,
                                                      const float* __restrict__ cat,
                                                      float* __restrict__ out) {
  __shared__ float cs[2][512 * CK];  // 2 x 32 KiB
  __shared__ float part[4][4];
  __shared__ float rs[4];
  __shared__ float red[4][4][2];  // [row][wave][val, idx]

  const int t = threadIdx.x;
  const int lane = t & 63;
  const int w = t >> 6;
  const int bm0 = blockIdx.x * 4;

  // ---- per-lane staging source offsets (inverse-swizzled global source) ----
  int soff[8];
#pragma unroll
  for (int i = 0; i < 8; ++i) {
    const int G = w * 512 + i * 64 + lane;
    const int col = G >> 2;
    const int g = (G & 3) ^ ((G >> 3) & 3);
    soff[i] = col * ND + g * 4;
  }

#define STAGE(buf, ck)                                              \
  do {                                                              \
    _Pragma("unroll") for (int i = 0; i < 8; ++i)                   \
        load_lds16(cat + soff[i] + (ck) * CK,                       \
                   &cs[buf][w * 2048 + i * 256]);                   \
  } while (0)

  STAGE(0, 0);

  // ---- row sums: summation order identical to rounds 1-4 (bit-exact) ----
  if (t < 16) {
    const int r = t >> 2, seg = t & 3;
    const float4* xr =
        reinterpret_cast<const float4*>(x + (size_t)(bm0 + r) * ND + seg * 64);
    float s = 0.f;
#pragma unroll
    for (int i = 0; i < 16; ++i) {
      float4 v = xr[i];
      s += v.x + v.y + v.z + v.w;
    }
    part[r][seg] = s;
  }
  __syncthreads();  // stage-0 drained + part visible
  if (t < 4) rs[t] = part[t][0] + part[t][1] + part[t][2] + part[t][3];

  const int c0 = w * 128 + lane;  // second col = c0 + 64, same swizzle key
  const int s0 = (c0 >> 1) & 3;
  const float* xr0 = x + (size_t)bm0 * ND;  // block-uniform -> scalar loads

  f2 a0 = {0.f, 0.f}, a1 = {0.f, 0.f}, a2 = {0.f, 0.f}, a3 = {0.f, 0.f};

#pragma unroll 1
  for (int ck = 0; ck < NCHK; ++ck) {
    if (ck + 1 < NCHK) {
      if ((ck & 1) == 0) STAGE(1, ck + 1); else STAGE(0, ck + 1);
    }
    const float* cb = &cs[ck & 1][0];
    const float* xq = xr0 + ck * CK;
#pragma unroll
    for (int k2 = 0; k2 < 4; ++k2) {
      const int sw = ((k2 ^ s0) << 2);
      const float4 cv0 = *reinterpret_cast<const float4*>(&cb[c0 * 16 + sw]);
      const float4 cv1 =
          *reinterpret_cast<const float4*>(&cb[(c0 + 64) * 16 + sw]);
      const float4 x0 = *reinterpret_cast<const float4*>(xq + k2 * 4);
      const float4 x1 = *reinterpret_cast<const float4*>(xq + ND + k2 * 4);
      const float4 x2 = *reinterpret_cast<const float4*>(xq + 2 * ND + k2 * 4);
      const float4 x3 = *reinterpret_cast<const float4*>(xq + 3 * ND + k2 * 4);
      // per k (ascending): 2 scalar mins + 1 packed add per row
      a0 += (f2){fminf(x0.x, cv0.x), fminf(x0.x, cv1.x)};
      a0 += (f2){fminf(x0.y, cv0.y), fminf(x0.y, cv1.y)};
      a0 += (f2){fminf(x0.z, cv0.z), fminf(x0.z, cv1.z)};
      a0 += (f2){fminf(x0.w, cv0.w), fminf(x0.w, cv1.w)};
      a1 += (f2){fminf(x1.x, cv0.x), fminf(x1.x, cv1.x)};
      a1 += (f2){fminf(x1.y, cv0.y), fminf(x1.y, cv1.y)};
      a1 += (f2){fminf(x1.z, cv0.z), fminf(x1.z, cv1.z)};
      a1 += (f2){fminf(x1.w, cv0.w), fminf(x1.w, cv1.w)};
      a2 += (f2){fminf(x2.x, cv0.x), fminf(x2.x, cv1.x)};
      a2 += (f2){fminf(x2.y, cv0.y), fminf(x2.y, cv1.y)};
      a2 += (f2){fminf(x2.z, cv0.z), fminf(x2.z, cv1.z)};
      a2 += (f2){fminf(x2.w, cv0.w), fminf(x2.w, cv1.w)};
      a3 += (f2){fminf(x3.x, cv0.x), fminf(x3.x, cv1.x)};
      a3 += (f2){fminf(x3.y, cv0.y), fminf(x3.y, cv1.y)};
      a3 += (f2){fminf(x3.z, cv0.z), fminf(x3.z, cv1.z)};
      a3 += (f2){fminf(x3.w, cv0.w), fminf(x3.w, cv1.w)};
    }
    __syncthreads();
  }

  // ---- epilogue: divide, threshold, store scores, fused argmax ----
  const float r0 = rs[0], r1 = rs[1], r2 = rs[2], r3 = rs[3];
  float v00 = a0.x / r0, v01 = a0.y / r0;
  float v10 = a1.x / r1, v11 = a1.y / r1;
  float v20 = a2.x / r2, v21 = a2.y / r2;
  float v30 = a3.x / r3, v31 = a3.y / r3;
  v00 = (v00 >= VIG) ? v00 : 0.f;  v01 = (v01 >= VIG) ? v01 : 0.f;
  v10 = (v10 >= VIG) ? v10 : 0.f;  v11 = (v11 >= VIG) ? v11 : 0.f;
  v20 = (v20 >= VIG) ? v20 : 0.f;  v21 = (v21 >= VIG) ? v21 : 0.f;
  v30 = (v30 >= VIG) ? v30 : 0.f;  v31 = (v31 >= VIG) ? v31 : 0.f;

  float* o0 = out + (size_t)bm0 * NC + c0;
  o0[0] = v00;            o0[64] = v01;
  o0[NC] = v10;           o0[NC + 64] = v11;
  o0[2 * NC] = v20;       o0[2 * NC + 64] = v21;
  o0[3 * NC] = v30;       o0[3 * NC + 64] = v31;

  // per-row wave-level argmax (lane cols c0 < c0+64; strict > keeps low col)
#pragma unroll
  for (int r = 0; r < 4; ++r) {
    float v0, v1;
    if (r == 0) { v0 = v00; v1 = v01; }
    else if (r == 1) { v0 = v10; v1 = v11; }
    else if (r == 2) { v0 = v20; v1 = v21; }
    else { v0 = v30; v1 = v31; }
    float bv = v0;
    int bi = c0;
    if (v1 > bv) { bv = v1; bi = c0 + 64; }
#pragma unroll
    for (int off = 32; off > 0; off >>= 1) {
      float ob = __shfl_xor(bv, off, 64);
      int oi = __shfl_xor(bi, off, 64);
      if (ob > bv || (ob == bv && oi < bi)) { bv = ob; bi = oi; }
    }
    if (lane == 0) { red[r][w][0] = bv; red[r][w][1] = (float)bi; }
  }
  __syncthreads();
  if (t < 4) {
    float bv = red[t][0][0];
    float bi = red[t][0][1];
#pragma unroll
    for (int w2 = 1; w2 < 4; ++w2) {
      float ov = red[t][w2][0], oi = red[t][w2][1];
      if (ov > bv) { bv = ov; bi = oi; }  // strict >: lower wave = lower cols
    }
    out[(size_t)NB * NC + bm0 + t] = bi;
  }
#undef STAGE
}

extern "C" void kernel_launch(void* const* d_in, const int* in_sizes, int n_in,
                              void* d_out, int out_size, void* d_ws, size_t ws_size,
                              hipStream_t stream) {
  const float* x = (const float*)d_in[0];
  const float* cat = (const float*)d_in[1];
  float* out = (float*)d_out;

  fuzzy_fused<<<NB / 4, 256, 0, stream>>>(x, cat, out);
}